// Round 1
// baseline (354.790 us; speedup 1.0000x reference)
//
#include <hip/hip_runtime.h>
#include <math.h>

// ---- problem constants ----
// D = 640; NET1=[640,512,64]; NET3=[640,640,512,64,512]
// W_TOTAL = 640*640 + 640*512 + 512*64 + 64*512 = 802816 ; B_TOTAL = 1728
// net2_w3: (804544, 64) row-major; x2[r] = 0.5*tanh(dot64(w3[r,:], h) + b3[r])

// workspace layout (float offsets)
#define WS_H0    0      // 640  : leaky(net2_w0@inpt+b0)
#define WS_H1N1  640    // 512  : leaky(net1_w0@inpt+b0)
#define WS_H1N2  1152   // 512  : leaky(net2_w1@h0+b1)
#define WS_H2    1664   // 64   : leaky(net2_w2@h1n2+b2)  == "h" for W3
#define WS_INPT  1728   // 640  : concat(x, prev_output, state)
#define WS_X3A   2368   // 640  : generated layer1 out
#define WS_X3B   3008   // 512  : generated layer2 out
#define WS_X3C   3520   // 64   : generated layer3 out

__device__ __forceinline__ float leaky_f(float v) { return v >= 0.0f ? v : 0.01f * v; }

__device__ __forceinline__ float inpt_at(int i, const float* x, const float* po, const float* st) {
  return i < 64 ? x[i] : (i < 128 ? po[i - 64] : st[i - 128]);
}

// ---------- K1a: h0 = leaky(net2_w0@inpt+b0) [640], h1n1 = leaky(net1_w0@inpt+b0) [512]
// one wave per output neuron; 288 blocks x 256 threads
__global__ __launch_bounds__(256) void k1a(const float* __restrict__ x, const float* __restrict__ po,
                                           const float* __restrict__ st,
                                           const float* __restrict__ w2_0, const float* __restrict__ b2_0,
                                           const float* __restrict__ w1_0, const float* __restrict__ b1_0,
                                           float* __restrict__ ws) {
  __shared__ float s_in[640];
  for (int i = threadIdx.x; i < 640; i += 256) {
    float v = inpt_at(i, x, po, st);
    s_in[i] = v;
    ws[WS_INPT + i] = v;  // materialize inpt for generated layer 1
  }
  __syncthreads();
  int wave = threadIdx.x >> 6, lane = threadIdx.x & 63;
  int o = blockIdx.x * 4 + wave;  // 0..1151
  const float* wrow;
  float bias;
  float* dst;
  if (o < 640) {
    wrow = w2_0 + (long long)o * 640; bias = b2_0[o]; dst = ws + WS_H0 + o;
  } else {
    int oo = o - 640;
    wrow = w1_0 + (long long)oo * 640; bias = b1_0[oo]; dst = ws + WS_H1N1 + oo;
  }
  float acc = 0.0f;
  for (int i = lane; i < 640; i += 64) acc += wrow[i] * s_in[i];
  for (int off = 32; off; off >>= 1) acc += __shfl_xor(acc, off, 64);
  if (lane == 0) *dst = leaky_f(acc + bias);
}

// ---------- K1b: h1n2 = leaky(net2_w1@h0+b1) [512] ; out = net1_w1@h1n1+b1 [64] -> d_out[0:64]
// 144 blocks x 256 threads (576 waves)
__global__ __launch_bounds__(256) void k1b(const float* __restrict__ w2_1, const float* __restrict__ b2_1,
                                           const float* __restrict__ w1_1, const float* __restrict__ b1_1,
                                           float* __restrict__ ws, float* __restrict__ out) {
  __shared__ float s_h0[640];
  __shared__ float s_h1[512];
  for (int i = threadIdx.x; i < 640; i += 256) s_h0[i] = ws[WS_H0 + i];
  for (int i = threadIdx.x; i < 512; i += 256) s_h1[i] = ws[WS_H1N1 + i];
  __syncthreads();
  int wave = threadIdx.x >> 6, lane = threadIdx.x & 63;
  int o = blockIdx.x * 4 + wave;  // 0..575
  float acc = 0.0f;
  if (o < 512) {
    const float* wrow = w2_1 + (long long)o * 640;
    for (int i = lane; i < 640; i += 64) acc += wrow[i] * s_h0[i];
    for (int off = 32; off; off >>= 1) acc += __shfl_xor(acc, off, 64);
    if (lane == 0) ws[WS_H1N2 + o] = leaky_f(acc + b2_1[o]);
  } else {
    int oo = o - 512;
    const float* wrow = w1_1 + (long long)oo * 512;
    for (int i = lane; i < 512; i += 64) acc += wrow[i] * s_h1[i];
    for (int off = 32; off; off >>= 1) acc += __shfl_xor(acc, off, 64);
    if (lane == 0) out[oo] = acc + b1_1[oo];  // no activation on net1 output
  }
}

// ---------- K1c: h2 = leaky(net2_w2@h1n2+b2) [64]
// 16 blocks x 256 threads
__global__ __launch_bounds__(256) void k1c(const float* __restrict__ w2_2, const float* __restrict__ b2_2,
                                           float* __restrict__ ws) {
  __shared__ float s_h[512];
  for (int i = threadIdx.x; i < 512; i += 256) s_h[i] = ws[WS_H1N2 + i];
  __syncthreads();
  int wave = threadIdx.x >> 6, lane = threadIdx.x & 63;
  int o = blockIdx.x * 4 + wave;  // 0..63
  const float* wrow = w2_2 + (long long)o * 512;
  float acc = 0.0f;
  for (int i = lane; i < 512; i += 64) acc += wrow[i] * s_h[i];
  for (int off = 32; off; off >>= 1) acc += __shfl_xor(acc, off, 64);
  if (lane == 0) ws[WS_H2 + o] = leaky_f(acc + b2_2[o]);
}

// ---------- K2: fused generated layer.
// x3out[o] = act( sum_i 0.5*tanh(w3[wi+o*IN+i,:]·h + b3[...]) * x3in[i]  + genbias[o] )
// genbias[o] comes from w3 row (brow + o).
// One output neuron per block (256 threads); lane-per-row, h in registers.
template <int IN_D, bool LEAKY>
__global__ __launch_bounds__(256) void k2(const float* __restrict__ w3, const float* __restrict__ b3,
                                          const float* __restrict__ h2p, const float* __restrict__ x3in,
                                          float* __restrict__ x3out, long long wi, long long brow) {
  __shared__ float s_in[IN_D];
  __shared__ float s_red[4];
  // h (64 floats) into registers
  float h[64];
  const float4* h4 = (const float4*)h2p;
#pragma unroll
  for (int k = 0; k < 16; k++) {
    float4 v = h4[k];
    h[4 * k + 0] = v.x; h[4 * k + 1] = v.y; h[4 * k + 2] = v.z; h[4 * k + 3] = v.w;
  }
  for (int i = threadIdx.x; i < IN_D; i += 256) s_in[i] = x3in[i];
  __syncthreads();

  int o = blockIdx.x;
  float acc = 0.0f;
  for (int i = threadIdx.x; i < IN_D; i += 256) {
    long long r = wi + (long long)o * IN_D + i;
    const float4* row = (const float4*)(w3 + r * 64);
    float d = 0.0f;
#pragma unroll
    for (int k = 0; k < 16; k++) {
      float4 v = row[k];
      d += v.x * h[4 * k + 0] + v.y * h[4 * k + 1] + v.z * h[4 * k + 2] + v.w * h[4 * k + 3];
    }
    float x2v = 0.5f * tanhf(d + b3[r]);
    acc += x2v * s_in[i];
  }
  for (int off = 32; off; off >>= 1) acc += __shfl_xor(acc, off, 64);
  int wave = threadIdx.x >> 6, lane = threadIdx.x & 63;
  if (lane == 0) s_red[wave] = acc;
  __syncthreads();
  if (threadIdx.x == 0) {
    float tot = s_red[0] + s_red[1] + s_red[2] + s_red[3];
    long long rb = brow + o;
    const float4* row = (const float4*)(w3 + rb * 64);
    float d = 0.0f;
#pragma unroll
    for (int k = 0; k < 16; k++) {
      float4 v = row[k];
      d += v.x * h[4 * k + 0] + v.y * h[4 * k + 1] + v.z * h[4 * k + 2] + v.w * h[4 * k + 3];
    }
    float gb = 0.5f * tanhf(d + b3[rb]);
    float res = tot + gb;
    x3out[o] = LEAKY ? leaky_f(res) : res;
  }
}

// ---------- K2d: generated layer 4 (out 512, in 64), no activation -> d_out[64:576]
// one wave per output; 128 blocks x 256 threads
__global__ __launch_bounds__(256) void k2d(const float* __restrict__ w3, const float* __restrict__ b3,
                                           const float* __restrict__ ws, float* __restrict__ out) {
  const float* h2p = ws + WS_H2;
  float h[64];
  const float4* h4 = (const float4*)h2p;
#pragma unroll
  for (int k = 0; k < 16; k++) {
    float4 v = h4[k];
    h[4 * k + 0] = v.x; h[4 * k + 1] = v.y; h[4 * k + 2] = v.z; h[4 * k + 3] = v.w;
  }
  int wave = threadIdx.x >> 6, lane = threadIdx.x & 63;
  int o = blockIdx.x * 4 + wave;  // 0..511
  long long r = 770048LL + (long long)o * 64 + lane;
  const float4* row = (const float4*)(w3 + r * 64);
  float d = 0.0f;
#pragma unroll
  for (int k = 0; k < 16; k++) {
    float4 v = row[k];
    d += v.x * h[4 * k + 0] + v.y * h[4 * k + 1] + v.z * h[4 * k + 2] + v.w * h[4 * k + 3];
  }
  float x2v = 0.5f * tanhf(d + b3[r]);
  float acc = x2v * ws[WS_X3C + lane];
  for (int off = 32; off; off >>= 1) acc += __shfl_xor(acc, off, 64);
  if (lane == 0) {
    long long rb = 804032LL + o;  // W_TOTAL + 1216 + o
    const float4* brow = (const float4*)(w3 + rb * 64);
    float db = 0.0f;
#pragma unroll
    for (int k = 0; k < 16; k++) {
      float4 v = brow[k];
      db += v.x * h[4 * k + 0] + v.y * h[4 * k + 1] + v.z * h[4 * k + 2] + v.w * h[4 * k + 3];
    }
    float gb = 0.5f * tanhf(db + b3[rb]);
    out[64 + o] = acc + gb;  // last layer: no leaky
  }
}

extern "C" void kernel_launch(void* const* d_in, const int* in_sizes, int n_in,
                              void* d_out, int out_size, void* d_ws, size_t ws_size,
                              hipStream_t stream) {
  const float* x    = (const float*)d_in[0];
  const float* po   = (const float*)d_in[1];
  const float* st   = (const float*)d_in[2];
  const float* w1_0 = (const float*)d_in[3];
  const float* b1_0 = (const float*)d_in[4];
  const float* w1_1 = (const float*)d_in[5];
  const float* b1_1 = (const float*)d_in[6];
  const float* w2_0 = (const float*)d_in[7];
  const float* b2_0 = (const float*)d_in[8];
  const float* w2_1 = (const float*)d_in[9];
  const float* b2_1 = (const float*)d_in[10];
  const float* w2_2 = (const float*)d_in[11];
  const float* b2_2 = (const float*)d_in[12];
  const float* w3   = (const float*)d_in[13];
  const float* b3   = (const float*)d_in[14];
  float* ws  = (float*)d_ws;
  float* out = (float*)d_out;

  k1a<<<288, 256, 0, stream>>>(x, po, st, w2_0, b2_0, w1_0, b1_0, ws);
  k1b<<<144, 256, 0, stream>>>(w2_1, b2_1, w1_1, b1_1, ws, out);
  k1c<<<16, 256, 0, stream>>>(w2_2, b2_2, ws);
  // generated layer 1: out 640, in 640, wi=0, bias rows start 802816
  k2<640, true><<<640, 256, 0, stream>>>(w3, b3, ws + WS_H2, ws + WS_INPT, ws + WS_X3A, 0LL, 802816LL);
  // generated layer 2: out 512, in 640, wi=409600, bias rows 803456
  k2<640, true><<<512, 256, 0, stream>>>(w3, b3, ws + WS_H2, ws + WS_X3A, ws + WS_X3B, 409600LL, 803456LL);
  // generated layer 3: out 64, in 512, wi=737280, bias rows 803968
  k2<512, true><<<64, 256, 0, stream>>>(w3, b3, ws + WS_H2, ws + WS_X3B, ws + WS_X3C, 737280LL, 803968LL);
  // generated layer 4: out 512, in 64, wi=770048, bias rows 804032 -> d_out[64:]
  k2d<<<128, 256, 0, stream>>>(w3, b3, ws, out);
}

// Round 2
// 351.322 us; speedup vs baseline: 1.0099x; 1.0099x over previous
//
#include <hip/hip_runtime.h>
#include <math.h>

// ---- problem constants ----
// D = 640; NET1=[640,512,64]; NET3=[640,640,512,64,512]
// W_TOTAL = 802816 ; B_TOTAL = 1728 ; x2 rows = 804544, each 64 wide
// weight row offsets: L1 wi=0, L2 wi=409600, L3 wi=737280, L4 wi=770048
// bias rows: L1 802816, L2 803456, L3 803968, L4 804032

// workspace layout (float offsets)
#define WS_H0    0      // 640
#define WS_H1N1  640    // 512
#define WS_H1N2  1152   // 512
#define WS_H2    1664   // 64   : "h" for W3
#define WS_INPT  1728   // 640
#define WS_X3A   2368   // 640
#define WS_X3B   3008   // 512
#define WS_X3C   3520   // 64

__device__ __forceinline__ float leaky_f(float v) { return v >= 0.0f ? v : 0.01f * v; }

// wave-uniform value -> SGPR
__device__ __forceinline__ float uni(float v) {
  return __int_as_float(__builtin_amdgcn_readfirstlane(__float_as_int(v)));
}

__device__ __forceinline__ float inpt_at(int i, const float* x, const float* po, const float* st) {
  return i < 64 ? x[i] : (i < 128 ? po[i - 64] : st[i - 128]);
}

// x2[r] = 0.5*tanh(w3[r,:]·h + b3[r]) = 0.5 - 1/(exp(2d)+1)
__device__ __forceinline__ float x2val(const float* __restrict__ w3, const float* __restrict__ b3,
                                       long long r, const float* hs) {
  const float4* row = (const float4*)(w3 + (r << 6));
  float d0 = 0.f, d1 = 0.f, d2 = 0.f, d3 = 0.f;
#pragma unroll
  for (int k = 0; k < 16; k++) {
    float4 v = row[k];
    d0 = fmaf(v.x, hs[4 * k + 0], d0);
    d1 = fmaf(v.y, hs[4 * k + 1], d1);
    d2 = fmaf(v.z, hs[4 * k + 2], d2);
    d3 = fmaf(v.w, hs[4 * k + 3], d3);
  }
  float d = ((d0 + d1) + (d2 + d3)) + b3[r];
  float t = exp2f(d * 2.8853900817779268f);  // exp(2d)
  return 0.5f - __builtin_amdgcn_rcpf(t + 1.0f);
}

__device__ __forceinline__ void load_h_uniform(const float* __restrict__ h2p, float* hs) {
  const float4* h4 = (const float4*)h2p;
#pragma unroll
  for (int k = 0; k < 16; k++) {
    float4 v = h4[k];
    hs[4 * k + 0] = uni(v.x);
    hs[4 * k + 1] = uni(v.y);
    hs[4 * k + 2] = uni(v.z);
    hs[4 * k + 3] = uni(v.w);
  }
}

// float4 dot of a weight row (IN floats) against LDS vector, wave-parallel
template <int IN>
__device__ __forceinline__ float row_dot(const float* __restrict__ wrow, const float* s_in, int lane) {
  const float4* w4 = (const float4*)wrow;
  const float4* s4 = (const float4*)s_in;
  float acc = 0.f;
  for (int j = lane; j < IN / 4; j += 64) {
    float4 a = w4[j];
    float4 b = s4[j];
    acc += a.x * b.x + a.y * b.y + a.z * b.z + a.w * b.w;
  }
  for (int off = 32; off; off >>= 1) acc += __shfl_xor(acc, off, 64);
  return acc;
}

// ---------- K1a: h0 = leaky(net2_w0@inpt+b0) [640], h1n1 = leaky(net1_w0@inpt+b0) [512]
__global__ __launch_bounds__(256) void k1a(const float* __restrict__ x, const float* __restrict__ po,
                                           const float* __restrict__ st,
                                           const float* __restrict__ w2_0, const float* __restrict__ b2_0,
                                           const float* __restrict__ w1_0, const float* __restrict__ b1_0,
                                           float* __restrict__ ws) {
  __shared__ __align__(16) float s_in[640];
  for (int i = threadIdx.x; i < 640; i += 256) {
    float v = inpt_at(i, x, po, st);
    s_in[i] = v;
    ws[WS_INPT + i] = v;
  }
  __syncthreads();
  int wave = threadIdx.x >> 6, lane = threadIdx.x & 63;
  int o = blockIdx.x * 4 + wave;  // 0..1151
  const float* wrow;
  float bias;
  float* dst;
  if (o < 640) {
    wrow = w2_0 + (long long)o * 640; bias = b2_0[o]; dst = ws + WS_H0 + o;
  } else {
    int oo = o - 640;
    wrow = w1_0 + (long long)oo * 640; bias = b1_0[oo]; dst = ws + WS_H1N1 + oo;
  }
  float acc = row_dot<640>(wrow, s_in, lane);
  if (lane == 0) *dst = leaky_f(acc + bias);
}

// ---------- K1b: h1n2 = leaky(net2_w1@h0+b1) [512] ; out = net1_w1@h1n1+b1 [64]
__global__ __launch_bounds__(256) void k1b(const float* __restrict__ w2_1, const float* __restrict__ b2_1,
                                           const float* __restrict__ w1_1, const float* __restrict__ b1_1,
                                           float* __restrict__ ws, float* __restrict__ out) {
  __shared__ __align__(16) float s_h0[640];
  __shared__ __align__(16) float s_h1[512];
  for (int i = threadIdx.x; i < 640; i += 256) s_h0[i] = ws[WS_H0 + i];
  for (int i = threadIdx.x; i < 512; i += 256) s_h1[i] = ws[WS_H1N1 + i];
  __syncthreads();
  int wave = threadIdx.x >> 6, lane = threadIdx.x & 63;
  int o = blockIdx.x * 4 + wave;  // 0..575
  if (o < 512) {
    float acc = row_dot<640>(w2_1 + (long long)o * 640, s_h0, lane);
    if (lane == 0) ws[WS_H1N2 + o] = leaky_f(acc + b2_1[o]);
  } else {
    int oo = o - 512;
    float acc = row_dot<512>(w1_1 + (long long)oo * 512, s_h1, lane);
    if (lane == 0) out[oo] = acc + b1_1[oo];
  }
}

// ---------- K1c: h2 = leaky(net2_w2@h1n2+b2) [64]
__global__ __launch_bounds__(256) void k1c(const float* __restrict__ w2_2, const float* __restrict__ b2_2,
                                           float* __restrict__ ws) {
  __shared__ __align__(16) float s_h[512];
  for (int i = threadIdx.x; i < 512; i += 256) s_h[i] = ws[WS_H1N2 + i];
  __syncthreads();
  int wave = threadIdx.x >> 6, lane = threadIdx.x & 63;
  int o = blockIdx.x * 4 + wave;  // 0..63
  float acc = row_dot<512>(w2_2 + (long long)o * 512, s_h, lane);
  if (lane == 0) ws[WS_H2 + o] = leaky_f(acc + b2_2[o]);
}

// ---------- K2: fused generated layer. One block (512 threads) per output neuron.
// x3out[o] = act( sum_i x2[wi+o*IN+i] * x3in[i] + x2[brow+o] )
template <int IN_D, bool LEAKY>
__global__ __launch_bounds__(512) void k2(const float* __restrict__ w3, const float* __restrict__ b3,
                                          const float* __restrict__ h2p, const float* __restrict__ x3in,
                                          float* __restrict__ x3out, long long wi, long long brow) {
  __shared__ __align__(16) float s_in[IN_D];
  __shared__ float s_red[8];
  float hs[64];
  load_h_uniform(h2p, hs);
  for (int i = threadIdx.x; i < IN_D; i += 512) s_in[i] = x3in[i];
  __syncthreads();

  int o = blockIdx.x;
  float acc = 0.0f;
  for (int i = threadIdx.x; i < IN_D; i += 512) {
    long long r = wi + (long long)o * IN_D + i;
    acc += x2val(w3, b3, r, hs) * s_in[i];
  }
  // generated bias: assign to thread 511 (which has the least main work)
  if (threadIdx.x == 511) acc += x2val(w3, b3, brow + o, hs);

  for (int off = 32; off; off >>= 1) acc += __shfl_xor(acc, off, 64);
  int wave = threadIdx.x >> 6, lane = threadIdx.x & 63;
  if (lane == 0) s_red[wave] = acc;
  __syncthreads();
  if (threadIdx.x == 0) {
    float tot = 0.f;
#pragma unroll
    for (int w = 0; w < 8; w++) tot += s_red[w];
    x3out[o] = LEAKY ? leaky_f(tot) : tot;
  }
}

// ---------- K2d: generated layer 4 (out 512, in 64) -> d_out[64:576], wave per output
__global__ __launch_bounds__(256) void k2d(const float* __restrict__ w3, const float* __restrict__ b3,
                                           const float* __restrict__ ws, float* __restrict__ out) {
  float hs[64];
  load_h_uniform(ws + WS_H2, hs);
  int wave = threadIdx.x >> 6, lane = threadIdx.x & 63;
  int o = blockIdx.x * 4 + wave;  // 0..511
  long long r = 770048LL + (long long)o * 64 + lane;
  float acc = x2val(w3, b3, r, hs) * ws[WS_X3C + lane];
  if (lane == 0) acc += x2val(w3, b3, 804032LL + o, hs);  // generated bias
  for (int off = 32; off; off >>= 1) acc += __shfl_xor(acc, off, 64);
  if (lane == 0) out[64 + o] = acc;  // last layer: no activation
}

extern "C" void kernel_launch(void* const* d_in, const int* in_sizes, int n_in,
                              void* d_out, int out_size, void* d_ws, size_t ws_size,
                              hipStream_t stream) {
  const float* x    = (const float*)d_in[0];
  const float* po   = (const float*)d_in[1];
  const float* st   = (const float*)d_in[2];
  const float* w1_0 = (const float*)d_in[3];
  const float* b1_0 = (const float*)d_in[4];
  const float* w1_1 = (const float*)d_in[5];
  const float* b1_1 = (const float*)d_in[6];
  const float* w2_0 = (const float*)d_in[7];
  const float* b2_0 = (const float*)d_in[8];
  const float* w2_1 = (const float*)d_in[9];
  const float* b2_1 = (const float*)d_in[10];
  const float* w2_2 = (const float*)d_in[11];
  const float* b2_2 = (const float*)d_in[12];
  const float* w3   = (const float*)d_in[13];
  const float* b3   = (const float*)d_in[14];
  float* ws  = (float*)d_ws;
  float* out = (float*)d_out;

  k1a<<<288, 256, 0, stream>>>(x, po, st, w2_0, b2_0, w1_0, b1_0, ws);
  k1b<<<144, 256, 0, stream>>>(w2_1, b2_1, w1_1, b1_1, ws, out);
  k1c<<<16, 256, 0, stream>>>(w2_2, b2_2, ws);
  k2<640, true><<<640, 512, 0, stream>>>(w3, b3, ws + WS_H2, ws + WS_INPT, ws + WS_X3A, 0LL, 802816LL);
  k2<640, true><<<512, 512, 0, stream>>>(w3, b3, ws + WS_H2, ws + WS_X3A, ws + WS_X3B, 409600LL, 803456LL);
  k2<512, true><<<64, 512, 0, stream>>>(w3, b3, ws + WS_H2, ws + WS_X3B, ws + WS_X3C, 737280LL, 803968LL);
  k2d<<<128, 256, 0, stream>>>(w3, b3, ws, out);
}